// Round 1
// baseline (10.772 us; speedup 1.0000x reference)
//
#include <hip/hip_runtime.h>

// MiniBatchAUC: loss = sum_{i in pos, j in neg} (1 - (s_i - s_j))^2 / (n_pos*n_neg)
// where s = sigmoid(logits). Expands to a closed form in 6 O(N) reductions:
//   loss_total = np*nn - 2*nn*Sp + 2*np*Sn + nn*Sp2 + np*Sn2 - 2*Sp*Sn
// Single block, 1024 threads; wave-64 shuffle reduce -> LDS -> thread 0 combine.

#define BLOCK 1024

__global__ __launch_bounds__(BLOCK) void auc_stats_kernel(
    const float* __restrict__ logits, const int* __restrict__ targets,
    float* __restrict__ out, int n) {
  const int tid = threadIdx.x;

  // acc: [0]=n_pos [1]=n_neg [2]=Sp [3]=Sn [4]=Sp2 [5]=Sn2
  float acc[6] = {0.f, 0.f, 0.f, 0.f, 0.f, 0.f};

  const int n4 = n >> 2;
  const float4* l4 = reinterpret_cast<const float4*>(logits);
  const int4*   t4 = reinterpret_cast<const int4*>(targets);

  for (int i = tid; i < n4; i += BLOCK) {
    float4 lv = l4[i];
    int4   tv = t4[i];
    float xs[4] = {lv.x, lv.y, lv.z, lv.w};
    int   ts[4] = {tv.x, tv.y, tv.z, tv.w};
#pragma unroll
    for (int k = 0; k < 4; ++k) {
      float s  = 1.0f / (1.0f + __expf(-xs[k]));
      float s2 = s * s;
      float p  = (ts[k] != 0) ? 1.0f : 0.0f;  // predicated, no divergence
      float q  = 1.0f - p;
      acc[0] += p;       acc[1] += q;
      acc[2] += p * s;   acc[3] += q * s;
      acc[4] += p * s2;  acc[5] += q * s2;
    }
  }
  // tail (n not multiple of 4) — not hit for N=16384 but kept for generality
  for (int i = (n4 << 2) + tid; i < n; i += BLOCK) {
    float s  = 1.0f / (1.0f + __expf(-logits[i]));
    float s2 = s * s;
    float p  = (targets[i] != 0) ? 1.0f : 0.0f;
    float q  = 1.0f - p;
    acc[0] += p;       acc[1] += q;
    acc[2] += p * s;   acc[3] += q * s;
    acc[4] += p * s2;  acc[5] += q * s2;
  }

  // wave-64 butterfly reduce
#pragma unroll
  for (int j = 0; j < 6; ++j) {
#pragma unroll
    for (int m = 1; m < 64; m <<= 1) {
      acc[j] += __shfl_xor(acc[j], m, 64);
    }
  }

  __shared__ float lds[BLOCK / 64][6];
  const int wave = tid >> 6;
  const int lane = tid & 63;
  if (lane == 0) {
#pragma unroll
    for (int j = 0; j < 6; ++j) lds[wave][j] = acc[j];
  }
  __syncthreads();

  if (tid == 0) {
    double t[6] = {0, 0, 0, 0, 0, 0};
    for (int w = 0; w < BLOCK / 64; ++w)
      for (int j = 0; j < 6; ++j) t[j] += (double)lds[w][j];

    double np_ = t[0], nn = t[1], sp = t[2], sn = t[3], sp2 = t[4], sn2 = t[5];
    double loss = np_ * nn
                - 2.0 * nn * sp
                + 2.0 * np_ * sn
                + nn * sp2
                + np_ * sn2
                - 2.0 * sp * sn;
    out[0] = (float)(loss / (np_ * nn));
  }
}

extern "C" void kernel_launch(void* const* d_in, const int* in_sizes, int n_in,
                              void* d_out, int out_size, void* d_ws, size_t ws_size,
                              hipStream_t stream) {
  const float* logits  = (const float*)d_in[0];
  const int*   targets = (const int*)d_in[1];
  float*       out     = (float*)d_out;
  const int n = in_sizes[0];

  auc_stats_kernel<<<dim3(1), dim3(BLOCK), 0, stream>>>(logits, targets, out, n);
}